// Round 2
// baseline (1242.692 us; speedup 1.0000x reference)
//
#include <hip/hip_runtime.h>

// LSTM decoder: B=1024, H=16 hidden, 4H=64 gates, T=128 outer steps,
// 16 inner cells per step, R=128 input dim for h0/c0.
//
// Mapping: one wave (64 lanes) processes NB=4 batch elements concurrently;
// lane j owns gate j for ALL four batches. The four recurrences are
// independent, so their VALU work fills each other's ds_bpermute/transcendental
// stall cycles (round 1 measured: 177 busy / 540 stalled cyc per cell at
// 1 batch/wave). Weights are batch-independent -> shared registers; only
// h[16], c, win[16] replicate per batch.

#define B_ 1024
#define A_ 16
#define T_ 128
#define R_ 128
#define H_ 16
#define NB 4

__global__ __launch_bounds__(64) void lstm_decoder_kernel(
    const float* __restrict__ y,     // (B,16)
    const float* __restrict__ u,     // (B,128)
    const float* __restrict__ W_ih,  // (64,1)
    const float* __restrict__ W_hh,  // (64,16)
    const float* __restrict__ b_ih,  // (64)
    const float* __restrict__ b_hh,  // (64)
    const float* __restrict__ W_lin, // (1,16)
    const float* __restrict__ b_lin, // (1)
    const float* __restrict__ W_h0,  // (16,128)
    const float* __restrict__ b_h0,  // (16)
    const float* __restrict__ W_c0,  // (16,128)
    const float* __restrict__ b_c0,  // (16)
    float* __restrict__ out)         // (B,144)
{
    const int b0 = blockIdx.x * NB;  // first batch element of this wave
    const int j  = threadIdx.x;      // gate index 0..63
    const int k  = j & 15;           // hidden index within gate group

    __shared__ float lds_u[R_];
    __shared__ float lds_h[NB][H_];
    __shared__ float lds_c[NB][H_];

    // ---- h0/c0 init, one batch at a time (tiny vs main loop) ----
    for (int nb = 0; nb < NB; ++nb) {
        const int b = b0 + nb;
        lds_u[j]      = u[b * R_ + j];
        lds_u[j + 64] = u[b * R_ + j + 64];
        __syncthreads();
        if (j < 32) {
            const float* Wr = (j < 16) ? (W_h0 + k * R_) : (W_c0 + k * R_);
            float acc = (j < 16) ? b_h0[k] : b_c0[k];
            #pragma unroll
            for (int r = 0; r < R_; r += 4) {
                float4 wv = *(const float4*)(Wr + r);
                float4 uv = *(const float4*)(&lds_u[r]);
                acc = fmaf(wv.x, uv.x, acc);
                acc = fmaf(wv.y, uv.y, acc);
                acc = fmaf(wv.z, uv.z, acc);
                acc = fmaf(wv.w, uv.w, acc);
            }
            if (j < 16) lds_h[nb][k] = acc;
            else        lds_c[nb][k] = acc;
        }
        __syncthreads();
    }

    // ---- shared (batch-independent) per-lane weights ----
    float w[H_];   // W_hh row j
    {
        float4 r0 = *(const float4*)(W_hh + j * H_ + 0);
        float4 r1 = *(const float4*)(W_hh + j * H_ + 4);
        float4 r2 = *(const float4*)(W_hh + j * H_ + 8);
        float4 r3 = *(const float4*)(W_hh + j * H_ + 12);
        w[0]=r0.x; w[1]=r0.y; w[2]=r0.z; w[3]=r0.w;
        w[4]=r1.x; w[5]=r1.y; w[6]=r1.z; w[7]=r1.w;
        w[8]=r2.x; w[9]=r2.y; w[10]=r2.z; w[11]=r2.w;
        w[12]=r3.x; w[13]=r3.y; w[14]=r3.z; w[15]=r3.w;
    }
    const float bj = b_ih[j] + b_hh[j];
    const float wi = W_ih[j];

    float wl[H_];
    #pragma unroll
    for (int m = 0; m < H_; ++m) wl[m] = W_lin[m];
    const float bl = b_lin[0];

    // ---- per-batch state ----
    float h[NB][H_];
    float c[NB];
    float win[NB][A_];
    float pout0[NB], pout1[NB];
    #pragma unroll
    for (int nb = 0; nb < NB; ++nb) {
        #pragma unroll
        for (int m = 0; m < H_; ++m) h[nb][m] = lds_h[nb][m];
        c[nb] = lds_c[nb][k];
        #pragma unroll
        for (int t = 0; t < A_; ++t) win[nb][t] = y[(b0 + nb) * A_ + t];
        pout0[nb] = 0.f; pout1[nb] = 0.f;
    }

    const bool isg = ((j >> 4) == 2);  // lanes 32..47 hold the g (tanh) gate

    for (int s = 0; s < T_; ++s) {
        #pragma unroll
        for (int t = 0; t < A_; ++t) {
            float gv[NB];
            // --- gate compute for all batches (independent -> ILP) ---
            #pragma unroll
            for (int nb = 0; nb < NB; ++nb) {
                const float x = win[nb][t];
                float a0 = fmaf(x, wi, bj);
                a0 = fmaf(h[nb][0], w[0], a0);
                float a1 = h[nb][1] * w[1];
                float a2 = h[nb][2] * w[2];
                float a3 = h[nb][3] * w[3];
                #pragma unroll
                for (int m = 4; m < H_; m += 4) {
                    a0 = fmaf(h[nb][m + 0], w[m + 0], a0);
                    a1 = fmaf(h[nb][m + 1], w[m + 1], a1);
                    a2 = fmaf(h[nb][m + 2], w[m + 2], a2);
                    a3 = fmaf(h[nb][m + 3], w[m + 3], a3);
                }
                const float z  = (a0 + a1) + (a2 + a3);
                const float z2 = isg ? (z + z) : z;
                const float e  = __expf(-z2);
                const float sg = __builtin_amdgcn_rcpf(1.0f + e);
                gv[nb] = isg ? fmaf(2.0f, sg, -1.0f) : sg;
            }
            // --- i/f/g/o exchange for all batches (shuffles overlap) ---
            float iv[NB], fv[NB], gg[NB], ov[NB];
            #pragma unroll
            for (int nb = 0; nb < NB; ++nb) {
                iv[nb] = __shfl(gv[nb], k,      64);
                fv[nb] = __shfl(gv[nb], k + 16, 64);
                gg[nb] = __shfl(gv[nb], k + 32, 64);
                ov[nb] = __shfl(gv[nb], k + 48, 64);
            }
            // --- c update + tanh (independent chains) ---
            float hk[NB];
            #pragma unroll
            for (int nb = 0; nb < NB; ++nb) {
                c[nb] = fmaf(fv[nb], c[nb], iv[nb] * gg[nb]);
                const float e2 = __expf(-2.0f * c[nb]);
                const float th = fmaf(2.0f, __builtin_amdgcn_rcpf(1.0f + e2), -1.0f);
                hk[nb] = ov[nb] * th;
            }
            // --- h rebroadcast (all NB*16 shuffles issue together) ---
            #pragma unroll
            for (int nb = 0; nb < NB; ++nb) {
                #pragma unroll
                for (int m = 0; m < H_; ++m) h[nb][m] = __shfl(hk[nb], m, 64);
            }
        }
        // --- pred + window slide per batch ---
        #pragma unroll
        for (int nb = 0; nb < NB; ++nb) {
            float p = bl;
            #pragma unroll
            for (int m = 0; m < H_; ++m) p = fmaf(h[nb][m], wl[m], p);
            #pragma unroll
            for (int t = 0; t < A_ - 1; ++t) win[nb][t] = win[nb][t + 1];
            win[nb][A_ - 1] = p;
            if (s == j)      pout0[nb] = p;
            if (s == j + 64) pout1[nb] = p;
        }
    }

    // ---- output: out[b,0:16]=y[b,:], out[b,16+s]=pred_s ----
    #pragma unroll
    for (int nb = 0; nb < NB; ++nb) {
        const int b = b0 + nb;
        if (j < A_) out[b * (A_ + T_) + j] = y[b * A_ + j];
        out[b * (A_ + T_) + A_ + j]      = pout0[nb];
        out[b * (A_ + T_) + A_ + 64 + j] = pout1[nb];
    }
}

extern "C" void kernel_launch(void* const* d_in, const int* in_sizes, int n_in,
                              void* d_out, int out_size, void* d_ws, size_t ws_size,
                              hipStream_t stream) {
    const float* y     = (const float*)d_in[0];
    const float* u     = (const float*)d_in[1];
    const float* W_ih  = (const float*)d_in[2];
    const float* W_hh  = (const float*)d_in[3];
    const float* b_ih  = (const float*)d_in[4];
    const float* b_hh  = (const float*)d_in[5];
    const float* W_lin = (const float*)d_in[6];
    const float* b_lin = (const float*)d_in[7];
    const float* W_h0  = (const float*)d_in[8];
    const float* b_h0  = (const float*)d_in[9];
    const float* W_c0  = (const float*)d_in[10];
    const float* b_c0  = (const float*)d_in[11];
    float* out = (float*)d_out;

    lstm_decoder_kernel<<<B_ / NB, 64, 0, stream>>>(
        y, u, W_ih, W_hh, b_ih, b_hh, W_lin, b_lin,
        W_h0, b_h0, W_c0, b_c0, out);
}

// Round 4
// 554.955 us; speedup vs baseline: 2.2393x; 2.2393x over previous
//
#include <hip/hip_runtime.h>

// LSTM decoder: B=1024, H=16, 4H=64 gates, T=128 steps x 16 cells = 2048
// strictly-serial cell evaluations per batch chain.
//
// Mapping: NB=1 (1024 waves = 1/SIMD, full machine), lane j, k=j&15.
// Each lane REDUNDANTLY computes all 4 gates (i,f,g,o) of hidden index k
// (4 dots x 16 FMA) so c[k] and h[k] are produced locally -- no cross-lane
// gate exchange. The only cross-lane event per cell is the h[0..15]
// broadcast: 1 ds_write_b32 + 4 ds_read_b128 (vs round-1's 20 ds_bpermute).
// Activation scaling (-log2e, and x2 for the g gate's tanh) is folded into
// pre-scaled weight copies so the dot feeds v_exp_f32 directly.
//
// Round-3 bug fixed here: tanh(c) fold had its fmaf args reversed,
// producing -tanh(c) (absmax 0.19). Correct: th = 2*rcp(1+e^{-2c}) - 1.

#define B_ 1024
#define A_ 16
#define T_ 128
#define R_ 128
#define H_ 16

__global__ __launch_bounds__(64) void lstm_decoder_kernel(
    const float* __restrict__ y,     // (B,16)
    const float* __restrict__ u,     // (B,128)
    const float* __restrict__ W_ih,  // (64,1)
    const float* __restrict__ W_hh,  // (64,16)
    const float* __restrict__ b_ih,  // (64)
    const float* __restrict__ b_hh,  // (64)
    const float* __restrict__ W_lin, // (1,16)
    const float* __restrict__ b_lin, // (1)
    const float* __restrict__ W_h0,  // (16,128)
    const float* __restrict__ b_h0,  // (16)
    const float* __restrict__ W_c0,  // (16,128)
    const float* __restrict__ b_c0,  // (16)
    float* __restrict__ out)         // (B,144)
{
    const int b = blockIdx.x;     // batch element
    const int j = threadIdx.x;    // lane 0..63
    const int k = j & 15;         // hidden index this lane owns (4x redundant)

    __shared__ float lds_u[R_];
    __shared__ float lds_h[H_];
    __shared__ float lds_c[H_];
    __shared__ __attribute__((aligned(16))) float lds_hb[64]; // h broadcast

    // ---- stage u[b,:] to LDS (coalesced) ----
    lds_u[j]      = u[b * R_ + j];
    lds_u[j + 64] = u[b * R_ + j + 64];
    __syncthreads();

    // ---- h0 / c0 init: lanes 0..15 -> h0[k], lanes 16..31 -> c0[k] ----
    if (j < 32) {
        const float* Wr = (j < 16) ? (W_h0 + k * R_) : (W_c0 + k * R_);
        float acc = (j < 16) ? b_h0[k] : b_c0[k];
        #pragma unroll
        for (int r = 0; r < R_; r += 4) {
            float4 wv = *(const float4*)(Wr + r);
            float4 uv = *(const float4*)(&lds_u[r]);
            acc = fmaf(wv.x, uv.x, acc);
            acc = fmaf(wv.y, uv.y, acc);
            acc = fmaf(wv.z, uv.z, acc);
            acc = fmaf(wv.w, uv.w, acc);
        }
        if (j < 16) lds_h[k] = acc;
        else        lds_c[k] = acc;
    }
    __syncthreads();

    // ---- pre-scaled weights: rows k, k+16, k+32, k+48 of W_hh ----
    // scale s_q = -log2e (i,f,o) or -2*log2e (g) so that
    // v_exp(dot) = e^{-z} (i,f,o) or e^{-2z} (g).
    const float LOG2E = 1.4426950408889634f;
    float w4[4][H_], b4[4], wi4[4];
    #pragma unroll
    for (int q = 0; q < 4; ++q) {
        const float s = (q == 2) ? (-2.0f * LOG2E) : (-LOG2E);
        const int row = k + 16 * q;
        float4 r0 = *(const float4*)(W_hh + row * H_ + 0);
        float4 r1 = *(const float4*)(W_hh + row * H_ + 4);
        float4 r2 = *(const float4*)(W_hh + row * H_ + 8);
        float4 r3 = *(const float4*)(W_hh + row * H_ + 12);
        w4[q][0]=s*r0.x;  w4[q][1]=s*r0.y;  w4[q][2]=s*r0.z;  w4[q][3]=s*r0.w;
        w4[q][4]=s*r1.x;  w4[q][5]=s*r1.y;  w4[q][6]=s*r1.z;  w4[q][7]=s*r1.w;
        w4[q][8]=s*r2.x;  w4[q][9]=s*r2.y;  w4[q][10]=s*r2.z; w4[q][11]=s*r2.w;
        w4[q][12]=s*r3.x; w4[q][13]=s*r3.y; w4[q][14]=s*r3.z; w4[q][15]=s*r3.w;
        b4[q]  = s * (b_ih[row] + b_hh[row]);
        wi4[q] = s * W_ih[row];
    }
    const float cK = -2.0f * LOG2E;   // for tanh(c)

    float wl[H_];
    #pragma unroll
    for (int m = 0; m < H_; ++m) wl[m] = W_lin[m];
    const float bl = b_lin[0];

    // ---- per-lane state ----
    float h[H_];
    #pragma unroll
    for (int m = 0; m < H_; ++m) h[m] = lds_h[m];
    float c = lds_c[k];

    float win[A_];
    #pragma unroll
    for (int t = 0; t < A_; ++t) win[t] = y[b * A_ + t];

    float pout0 = 0.f, pout1 = 0.f;

    for (int s = 0; s < T_; ++s) {
        #pragma unroll
        for (int t = 0; t < A_; ++t) {
            const float x = win[t];
            // ---- 4 gate dots (i,f,g,o for hidden index k), all local ----
            float z[4];
            #pragma unroll
            for (int q = 0; q < 4; ++q) {
                float a0 = fmaf(x, wi4[q], b4[q]);
                a0 = fmaf(h[0], w4[q][0], a0);
                float a1 = h[1] * w4[q][1];
                float a2 = h[2] * w4[q][2];
                float a3 = h[3] * w4[q][3];
                #pragma unroll
                for (int m = 4; m < H_; m += 4) {
                    a0 = fmaf(h[m + 0], w4[q][m + 0], a0);
                    a1 = fmaf(h[m + 1], w4[q][m + 1], a1);
                    a2 = fmaf(h[m + 2], w4[q][m + 2], a2);
                    a3 = fmaf(h[m + 3], w4[q][m + 3], a3);
                }
                z[q] = (a0 + a1) + (a2 + a3);
            }
            // ---- activations (dot feeds v_exp directly) ----
            const float iv = __builtin_amdgcn_rcpf(1.0f + __builtin_amdgcn_exp2f(z[0]));
            const float fv = __builtin_amdgcn_rcpf(1.0f + __builtin_amdgcn_exp2f(z[1]));
            const float gg = fmaf(2.0f, __builtin_amdgcn_rcpf(1.0f + __builtin_amdgcn_exp2f(z[2])), -1.0f);
            const float ov = __builtin_amdgcn_rcpf(1.0f + __builtin_amdgcn_exp2f(z[3]));
            // ---- c, h[k] update (local) ----
            c = fmaf(fv, c, iv * gg);
            const float ec = __builtin_amdgcn_exp2f(cK * c);           // e^{-2c}
            const float th = fmaf(2.0f, __builtin_amdgcn_rcpf(1.0f + ec), -1.0f); // tanh(c)
            const float hk = ov * th;
            // ---- single cross-lane event: broadcast h[0..15] ----
            lds_hb[j] = hk;                       // groups 0..3 write copies
            __builtin_amdgcn_wave_barrier();      // order write before reads
            float4 h0 = *(const float4*)&lds_hb[0];
            float4 h1 = *(const float4*)&lds_hb[4];
            float4 h2 = *(const float4*)&lds_hb[8];
            float4 h3 = *(const float4*)&lds_hb[12];
            h[0]=h0.x;  h[1]=h0.y;  h[2]=h0.z;  h[3]=h0.w;
            h[4]=h1.x;  h[5]=h1.y;  h[6]=h1.z;  h[7]=h1.w;
            h[8]=h2.x;  h[9]=h2.y;  h[10]=h2.z; h[11]=h2.w;
            h[12]=h3.x; h[13]=h3.y; h[14]=h3.z; h[15]=h3.w;
            __builtin_amdgcn_wave_barrier();      // keep next write after reads
        }
        // ---- pred + window slide (off critical path: consumed 16 cells later)
        float p = bl;
        #pragma unroll
        for (int m = 0; m < H_; ++m) p = fmaf(h[m], wl[m], p);
        #pragma unroll
        for (int t = 0; t < A_ - 1; ++t) win[t] = win[t + 1];
        win[A_ - 1] = p;
        if (s == j)      pout0 = p;
        if (s == j + 64) pout1 = p;
    }

    // ---- output: out[b,0:16]=y[b,:], out[b,16+s]=pred_s ----
    if (j < A_) out[b * (A_ + T_) + j] = y[b * A_ + j];
    out[b * (A_ + T_) + A_ + j]      = pout0;
    out[b * (A_ + T_) + A_ + 64 + j] = pout1;
}

extern "C" void kernel_launch(void* const* d_in, const int* in_sizes, int n_in,
                              void* d_out, int out_size, void* d_ws, size_t ws_size,
                              hipStream_t stream) {
    const float* y     = (const float*)d_in[0];
    const float* u     = (const float*)d_in[1];
    const float* W_ih  = (const float*)d_in[2];
    const float* W_hh  = (const float*)d_in[3];
    const float* b_ih  = (const float*)d_in[4];
    const float* b_hh  = (const float*)d_in[5];
    const float* W_lin = (const float*)d_in[6];
    const float* b_lin = (const float*)d_in[7];
    const float* W_h0  = (const float*)d_in[8];
    const float* b_h0  = (const float*)d_in[9];
    const float* W_c0  = (const float*)d_in[10];
    const float* b_c0  = (const float*)d_in[11];
    float* out = (float*)d_out;

    lstm_decoder_kernel<<<B_, 64, 0, stream>>>(
        y, u, W_ih, W_hh, b_ih, b_hh, W_lin, b_lin,
        W_h0, b_h0, W_c0, b_c0, out);
}